// Round 2
// baseline (335.751 us; speedup 1.0000x reference)
//
#include <hip/hip_runtime.h>
#include <hip/hip_bf16.h>

// Sparse encoder layer: 3x submanifold conv (27-pt) + strided conv (8-pt),
// 4x training-mode BN+ReLU. bf16 MFMA (fp32 accum) for all convs.
//
// R1: conv kernel reworked to 16 sites/wave (was 64) -> 8192 waves instead of
// 2048; latency-bound gather loop needs TLP, occupancy was the cap (19%).
//
// ws layout (bytes):
//   [0, 1024)         : stats, 4 stages x (sum[32], sumsq[32]) fp32
//   [1024, 56320)     : W1t  bf16 [27][32d][32c]  (c>=3 zero)
//   [56320, 111616)   : W2at bf16 [27][32][32]
//   [111616, 166912)  : W2bt bf16 [27][32][32]
//   [166912, 183296)  : W3t  bf16 [8][32][32]
//   [183296, +8.4MB)  : X  bf16 [N,32]   (x1)
//   next  8.4MB       : T  bf16 [N,32]   (t1/t2/ft2b)
//   next  8.4MB       : FB bf16 [N,32]   (featsb / br1 / s / x3)

typedef __bf16 bf16_8 __attribute__((ext_vector_type(8)));
typedef float  f32x4  __attribute__((ext_vector_type(4)));

#define EPSV 1e-5f

__device__ inline bf16_8 bzero8() {
    bf16_8 z;
#pragma unroll
    for (int i = 0; i < 8; ++i) z[i] = (__bf16)0.f;
    return z;
}

__global__ void k_zero(float* p, int n) {
    int t = blockIdx.x * blockDim.x + threadIdx.x;
    if (t < n) p[t] = 0.f;
}

// Transpose + bf16-cast all weights. W layouts in: [K][Cin][32d]; out: [K][32d][32c]
__global__ void k_prepw(const float* __restrict__ W1, const float* __restrict__ W2a,
                        const float* __restrict__ W2b, const float* __restrict__ W3,
                        __bf16* __restrict__ w1t, __bf16* __restrict__ w2at,
                        __bf16* __restrict__ w2bt, __bf16* __restrict__ w3t) {
    int t = blockIdx.x * blockDim.x + threadIdx.x;
    if (t < 27648) {
        int k = t >> 10, r = t & 1023, d = r >> 5, c = r & 31;
        w1t[t] = (c < 3) ? (__bf16)W1[(k * 3 + c) * 32 + d] : (__bf16)0.f;
    } else if (t < 2 * 27648) {
        int j = t - 27648;
        int k = j >> 10, r = j & 1023, d = r >> 5, c = r & 31;
        w2at[j] = (__bf16)W2a[(k * 32 + c) * 32 + d];
    } else if (t < 3 * 27648) {
        int j = t - 2 * 27648;
        int k = j >> 10, r = j & 1023, d = r >> 5, c = r & 31;
        w2bt[j] = (__bf16)W2b[(k * 32 + c) * 32 + d];
    } else if (t < 3 * 27648 + 8192) {
        int j = t - 3 * 27648;
        int k = j >> 10, r = j & 1023, d = r >> 5, c = r & 31;
        w3t[j] = (__bf16)W3[(k * 32 + c) * 32 + d];
    }
}

// feats fp32 [N,3] -> bf16 [N,32] zero-padded
__global__ void k_prepf(const float* __restrict__ f, __bf16* __restrict__ fb, int n32) {
    int t = blockIdx.x * blockDim.x + threadIdx.x;
    if (t < n32) {
        int s = t >> 5, c = t & 31;
        fb[t] = (c < 3) ? (__bf16)f[s * 3 + c] : (__bf16)0.f;
    }
}

// Gathered-GEMM conv. Per wave: 16 sites, full Cin=32 per MFMA,
// 2 MFMAs (d-halves) per offset. Epilogue: optional add (x1), bf16 store,
// per-channel sum/sumsq -> LDS -> global atomics.
template <int KOFF, bool ADD>
__global__ __launch_bounds__(256, 8) void k_conv(
    const __bf16* __restrict__ src,     // [Nsrc,32] bf16
    const int* __restrict__ idx,        // [nout,KOFF]
    const __bf16* __restrict__ Wt,      // [KOFF][32d][32c] bf16
    const __bf16* __restrict__ addsrc,  // [nout,32] bf16 or null
    __bf16* __restrict__ dst,           // [nout,32] bf16
    float* __restrict__ stats,          // [64]: sum[32], sumsq[32]
    int nout) {
    __shared__ float lst[64];
    const int tid = threadIdx.x;
    const int lane = tid & 63;
    const int wv = tid >> 6;
    const int base = blockIdx.x * 64 + wv * 16;
    if (tid < 64) lst[tid] = 0.f;
    __syncthreads();

    const int sl = lane & 15;   // A row / B col within 16
    const int kh = lane >> 4;   // k-quarter: channels kh*8..kh*8+7

    f32x4 acc0, acc1;
#pragma unroll
    for (int r = 0; r < 4; ++r) { acc0[r] = 0.f; acc1[r] = 0.f; }

    const int s = base + sl;
    const bool valid = (s < nout);
    const int* ip = idx + (size_t)(valid ? s : 0) * KOFF;

#pragma unroll
    for (int k = 0; k < KOFF; ++k) {
        int nb = valid ? ip[k] : -1;
        bf16_8 b0 = *(const bf16_8*)(Wt + k * 1024 + sl * 32 + kh * 8);
        bf16_8 b1 = *(const bf16_8*)(Wt + k * 1024 + (16 + sl) * 32 + kh * 8);
        bf16_8 a = *(const bf16_8*)(src + (size_t)(nb < 0 ? 0 : nb) * 32 + kh * 8);
        if (nb < 0) a = bzero8();
        acc0 = __builtin_amdgcn_mfma_f32_16x16x32_bf16(a, b0, acc0, 0, 0, 0);
        acc1 = __builtin_amdgcn_mfma_f32_16x16x32_bf16(a, b1, acc1, 0, 0, 0);
    }

    float s0 = 0.f, q0 = 0.f, s1 = 0.f, q1 = 0.f;
    const int rbase = kh * 4;  // C row = (lane>>4)*4 + reg
#pragma unroll
    for (int r = 0; r < 4; ++r) {
        int site = base + rbase + r;
        if (site < nout) {
            int o0 = site * 32 + sl;
            int o1 = o0 + 16;
            float v0 = acc0[r];
            float v1 = acc1[r];
            if (ADD) {
                v0 += (float)addsrc[o0];
                v1 += (float)addsrc[o1];
            }
            dst[o0] = (__bf16)v0;
            dst[o1] = (__bf16)v1;
            s0 += v0; q0 += v0 * v0;
            s1 += v1; q1 += v1 * v1;
        }
    }
    // reduce over the 4 lanes sharing each (d, dhalf): lanes {l, l^16, l^32, l^48}
    s0 += __shfl_xor(s0, 16); s0 += __shfl_xor(s0, 32);
    q0 += __shfl_xor(q0, 16); q0 += __shfl_xor(q0, 32);
    s1 += __shfl_xor(s1, 16); s1 += __shfl_xor(s1, 32);
    q1 += __shfl_xor(q1, 16); q1 += __shfl_xor(q1, 32);
    if (lane < 16) {
        atomicAdd(&lst[sl], s0);
        atomicAdd(&lst[32 + sl], q0);
    } else if (lane < 32) {
        atomicAdd(&lst[16 + sl], s1);
        atomicAdd(&lst[48 + sl], q1);
    }
    __syncthreads();
    if (tid < 64) atomicAdd(&stats[tid], lst[tid]);
}

// BN+ReLU apply: y = relu((x-mu)*rsqrt(var+eps)*g + b), stats from sums.
template <bool WF32, bool WBF>
__global__ __launch_bounds__(256) void k_bn(
    const __bf16* __restrict__ src, const float* __restrict__ st,
    const float* __restrict__ gamma, const float* __restrict__ beta,
    float inv_cnt, int nrows,
    float* __restrict__ dstf, __bf16* __restrict__ dstb) {
    int tid = blockIdx.x * blockDim.x + threadIdx.x;
    int c0 = (tid & 3) * 8;
    float scale[8], shift[8];
#pragma unroll
    for (int i = 0; i < 8; ++i) {
        int c = c0 + i;
        float mu = st[c] * inv_cnt;
        float var = st[32 + c] * inv_cnt - mu * mu;
        float sc = gamma[c] * rsqrtf(var + EPSV);
        scale[i] = sc;
        shift[i] = beta[c] - mu * sc;
    }
    int rstride = (gridDim.x * blockDim.x) >> 2;
    for (int r = tid >> 2; r < nrows; r += rstride) {
        int off = r * 32 + c0;
        bf16_8 v = *(const bf16_8*)(src + off);
        float y[8];
#pragma unroll
        for (int i = 0; i < 8; ++i) y[i] = fmaxf(fmaf((float)v[i], scale[i], shift[i]), 0.f);
        if (WBF) {
            bf16_8 o;
#pragma unroll
            for (int i = 0; i < 8; ++i) o[i] = (__bf16)y[i];
            *(bf16_8*)(dstb + off) = o;
        }
        if (WF32) {
            f32x4 lo, hi;
#pragma unroll
            for (int i = 0; i < 4; ++i) { lo[i] = y[i]; hi[i] = y[4 + i]; }
            *(f32x4*)(dstf + off) = lo;
            *(f32x4*)(dstf + off + 4) = hi;
        }
    }
}

extern "C" void kernel_launch(void* const* d_in, const int* in_sizes, int n_in,
                              void* d_out, int out_size, void* d_ws, size_t ws_size,
                              hipStream_t stream) {
    const float* feats = (const float*)d_in[0];
    const int* nbr     = (const int*)d_in[1];
    const int* child   = (const int*)d_in[2];
    const float* W1  = (const float*)d_in[3];
    const float* W2a = (const float*)d_in[4];
    const float* W2b = (const float*)d_in[5];
    const float* W3  = (const float*)d_in[6];
    const float* g1 = (const float*)d_in[7];  const float* b1 = (const float*)d_in[8];
    const float* g2 = (const float*)d_in[9];  const float* b2 = (const float*)d_in[10];
    const float* g3 = (const float*)d_in[11]; const float* b3 = (const float*)d_in[12];
    const float* g4 = (const float*)d_in[13]; const float* b4 = (const float*)d_in[14];

    const int N = in_sizes[0] / 3;   // 131072
    const int M = in_sizes[2] / 8;   // ~65k output sites of strided conv

    float* outp = (float*)d_out;               // [M,32]
    float* ft2p = outp + (size_t)M * 32;       // [N,32]

    char* ws = (char*)d_ws;
    float* stats = (float*)ws;
    __bf16* w1t  = (__bf16*)(ws + 1024);
    __bf16* w2at = w1t + 27648;
    __bf16* w2bt = w2at + 27648;
    __bf16* w3t  = w2bt + 27648;
    __bf16* X  = (__bf16*)(ws + 183296);
    __bf16* T  = X + (size_t)N * 32;
    __bf16* FB = T + (size_t)N * 32;

    float* s1 = stats;
    float* s2 = stats + 64;
    float* s3 = stats + 128;
    float* s4 = stats + 192;

    k_zero<<<1, 256, 0, stream>>>(stats, 256);
    k_prepw<<<(91136 + 255) / 256, 256, 0, stream>>>(W1, W2a, W2b, W3, w1t, w2at, w2bt, w3t);
    k_prepf<<<(N * 32 + 255) / 256, 256, 0, stream>>>(feats, FB, N * 32);

    const int cgrid = (N + 63) / 64;    // 16 sites/wave, 4 waves/block
    const int cgrid3 = (M + 63) / 64;

    // x1 = conv1(featsb)            FB -> X, stats s1
    k_conv<27, false><<<cgrid, 256, 0, stream>>>(FB, nbr, w1t, nullptr, X, s1, N);
    // t1 = bnrelu(x1)               X -> T
    k_bn<false, true><<<1024, 256, 0, stream>>>(X, s1, g1, b1, 1.f / N, N, nullptr, T);
    // br1 = conv2a(t1)              T -> FB, stats s2
    k_conv<27, false><<<cgrid, 256, 0, stream>>>(T, nbr, w2at, nullptr, FB, s2, N);
    // t2 = bnrelu(br1)              FB -> T
    k_bn<false, true><<<1024, 256, 0, stream>>>(FB, s2, g2, b2, 1.f / N, N, nullptr, T);
    // s = x1 + conv2b(t2)           T (+X) -> FB, stats s3
    k_conv<27, true><<<cgrid, 256, 0, stream>>>(T, nbr, w2bt, X, FB, s3, N);
    // ft2 = bnrelu(s)               FB -> d_out(ft2) fp32 + T bf16
    k_bn<true, true><<<1024, 256, 0, stream>>>(FB, s3, g3, b3, 1.f / N, N, ft2p, T);
    // x3 = conv3(ft2)               T -> FB, stats s4
    k_conv<8, false><<<cgrid3, 256, 0, stream>>>(T, child, w3t, nullptr, FB, s4, M);
    // out = bnrelu(x3)              FB -> d_out(out) fp32
    k_bn<true, false><<<1024, 256, 0, stream>>>(FB, s4, g4, b4, 1.f / M, M, outp, nullptr);
}

// Round 3
// 162.317 us; speedup vs baseline: 2.0685x; 2.0685x over previous
//
#include <hip/hip_runtime.h>
#include <hip/hip_bf16.h>

// Sparse encoder layer: 3x submanifold conv (27-pt) + strided conv (8-pt),
// 4x training-mode BN+ReLU. bf16 MFMA (fp32 accum) for all convs.
//
// R2: latency-bound gather loop. Split-K across the 4 waves of a block
// (each wave: 32 sites x ~7 offsets), ALL idx loads then ALL gathers issued
// up-front (one latency epoch, ~14 outstanding 64B gathers/wave), fp32
// partial accumulators reduced through LDS. Stats scatter over 32 partial
// copies to kill atomic serialization; BN kernels finalize in a prolog.
//
// ws layout (bytes):
//   [0, 32768)        : stats partials, 4 stages x 32 copies x 64 floats
//   [32768, +55296x3) : W1t/W2at/W2bt bf16 [27][32d][32c]
//   next 16384        : W3t bf16 [8][32][32]
//   then 3 x 8.4MB    : X, T, FB bf16 [N,32]

typedef __bf16 bf16_8 __attribute__((ext_vector_type(8)));
typedef float  f32x4  __attribute__((ext_vector_type(4)));

#define EPSV 1e-5f
#define NCOPY 32

__device__ inline bf16_8 bzero8() {
    bf16_8 z;
#pragma unroll
    for (int i = 0; i < 8; ++i) z[i] = (__bf16)0.f;
    return z;
}

__device__ inline bf16_8 gatherrow(const __bf16* __restrict__ src, int nb, int kh) {
    bf16_8 a = *(const bf16_8*)(src + (size_t)(nb < 0 ? 0 : nb) * 32 + kh * 8);
    if (nb < 0) a = bzero8();
    return a;
}

__global__ void k_zero(float* p, int n) {
    int t = blockIdx.x * blockDim.x + threadIdx.x;
    if (t < n) p[t] = 0.f;
}

// Transpose + bf16-cast all weights. In: [K][Cin][32d]; out: [K][32d][32c]
__global__ void k_prepw(const float* __restrict__ W1, const float* __restrict__ W2a,
                        const float* __restrict__ W2b, const float* __restrict__ W3,
                        __bf16* __restrict__ w1t, __bf16* __restrict__ w2at,
                        __bf16* __restrict__ w2bt, __bf16* __restrict__ w3t) {
    int t = blockIdx.x * blockDim.x + threadIdx.x;
    if (t < 27648) {
        int k = t >> 10, r = t & 1023, d = r >> 5, c = r & 31;
        w1t[t] = (c < 3) ? (__bf16)W1[(k * 3 + c) * 32 + d] : (__bf16)0.f;
    } else if (t < 2 * 27648) {
        int j = t - 27648;
        int k = j >> 10, r = j & 1023, d = r >> 5, c = r & 31;
        w2at[j] = (__bf16)W2a[(k * 32 + c) * 32 + d];
    } else if (t < 3 * 27648) {
        int j = t - 2 * 27648;
        int k = j >> 10, r = j & 1023, d = r >> 5, c = r & 31;
        w2bt[j] = (__bf16)W2b[(k * 32 + c) * 32 + d];
    } else if (t < 3 * 27648 + 8192) {
        int j = t - 3 * 27648;
        int k = j >> 10, r = j & 1023, d = r >> 5, c = r & 31;
        w3t[j] = (__bf16)W3[(k * 32 + c) * 32 + d];
    }
}

// feats fp32 [N,3] -> bf16 [N,32] zero-padded
__global__ void k_prepf(const float* __restrict__ f, __bf16* __restrict__ fb, int n32) {
    int t = blockIdx.x * blockDim.x + threadIdx.x;
    if (t < n32) {
        int s = t >> 5, c = t & 31;
        fb[t] = (c < 3) ? (__bf16)f[s * 3 + c] : (__bf16)0.f;
    }
}

// Split-K gathered-GEMM conv. Block = 4 waves, 32 output sites.
// Wave w: offsets [w*KPW, min(w*KPW+KPW, KOFF)), 2 groups of 16 sites.
// All idx then all gathers issued up-front; fp32 partials -> LDS -> reduce.
template <int KOFF, bool ADD>
__global__ __launch_bounds__(256, 4) void k_conv(
    const __bf16* __restrict__ src,     // [Nsrc,32] bf16
    const int* __restrict__ idx,        // [nout,KOFF]
    const __bf16* __restrict__ Wt,      // [KOFF][32d][32c] bf16
    const __bf16* __restrict__ addsrc,  // [nout,32] bf16 or null
    __bf16* __restrict__ dst,           // [nout,32] bf16
    float* __restrict__ spart,          // [NCOPY][64]: sum[32], sumsq[32]
    int nout) {
    constexpr int KPW = (KOFF + 3) / 4;
    __shared__ float part[4][32][33];
    __shared__ float lst[64];

    const int tid = threadIdx.x;
    const int lane = tid & 63;
    const int wv = tid >> 6;
    const int base = blockIdx.x * 32;
    const int sl = lane & 15;   // A row / B col within 16
    const int kh = lane >> 4;   // k-quarter: channels kh*8..kh*8+7
    const int kbeg = wv * KPW;

    if (tid < 64) lst[tid] = 0.f;

    // ---- all idx loads (independent, issued together) ----
    int nb[2][KPW];
#pragma unroll
    for (int g = 0; g < 2; ++g) {
        const int s = base + g * 16 + sl;
        const bool v = (s < nout);
        const int* ip = idx + (size_t)(v ? s : 0) * KOFF;
#pragma unroll
        for (int j = 0; j < KPW; ++j) {
            const bool kv = (kbeg + j) < KOFF;
            int t = ip[kv ? (kbeg + j) : 0];
            nb[g][j] = (v && kv) ? t : -1;
        }
    }

    // ---- all gathers (issued together; ~2*KPW outstanding) ----
    bf16_8 av[2][KPW];
#pragma unroll
    for (int j = 0; j < KPW; ++j)
#pragma unroll
        for (int g = 0; g < 2; ++g)
            av[g][j] = gatherrow(src, nb[g][j], kh);

    // ---- MFMA chain ----
    f32x4 acc[2][2];
#pragma unroll
    for (int g = 0; g < 2; ++g)
#pragma unroll
        for (int h = 0; h < 2; ++h)
#pragma unroll
            for (int r = 0; r < 4; ++r) acc[g][h][r] = 0.f;

#pragma unroll
    for (int j = 0; j < KPW; ++j) {
        int kk = kbeg + j;
        if (kk > KOFF - 1) kk = KOFF - 1;  // av is zero there; value irrelevant
        bf16_8 b0 = *(const bf16_8*)(Wt + kk * 1024 + sl * 32 + kh * 8);
        bf16_8 b1 = *(const bf16_8*)(Wt + kk * 1024 + (16 + sl) * 32 + kh * 8);
        acc[0][0] = __builtin_amdgcn_mfma_f32_16x16x32_bf16(av[0][j], b0, acc[0][0], 0, 0, 0);
        acc[0][1] = __builtin_amdgcn_mfma_f32_16x16x32_bf16(av[0][j], b1, acc[0][1], 0, 0, 0);
        acc[1][0] = __builtin_amdgcn_mfma_f32_16x16x32_bf16(av[1][j], b0, acc[1][0], 0, 0, 0);
        acc[1][1] = __builtin_amdgcn_mfma_f32_16x16x32_bf16(av[1][j], b1, acc[1][1], 0, 0, 0);
    }

    // ---- partials to LDS ----
#pragma unroll
    for (int g = 0; g < 2; ++g)
#pragma unroll
        for (int h = 0; h < 2; ++h)
#pragma unroll
            for (int r = 0; r < 4; ++r)
                part[wv][g * 16 + kh * 4 + r][h * 16 + sl] = acc[g][h][r];
    __syncthreads();

    // ---- reduce + epilogue (threads 0..127: 32 sites x 4 ch-blocks) ----
    if (tid < 128) {
        const int sloc = tid >> 2;
        const int c0 = (tid & 3) * 8;
        float v[8];
#pragma unroll
        for (int i = 0; i < 8; ++i)
            v[i] = part[0][sloc][c0 + i] + part[1][sloc][c0 + i] +
                   part[2][sloc][c0 + i] + part[3][sloc][c0 + i];
        const int site = base + sloc;
        if (site < nout) {
            if (ADD) {
                bf16_8 ad = *(const bf16_8*)(addsrc + (size_t)site * 32 + c0);
#pragma unroll
                for (int i = 0; i < 8; ++i) v[i] += (float)ad[i];
            }
            bf16_8 o;
#pragma unroll
            for (int i = 0; i < 8; ++i) o[i] = (__bf16)v[i];
            *(bf16_8*)(dst + (size_t)site * 32 + c0) = o;
        } else {
#pragma unroll
            for (int i = 0; i < 8; ++i) v[i] = 0.f;
        }
        float sv[8], qv[8];
#pragma unroll
        for (int i = 0; i < 8; ++i) { sv[i] = v[i]; qv[i] = v[i] * v[i]; }
#pragma unroll
        for (int d = 4; d < 64; d <<= 1) {
#pragma unroll
            for (int i = 0; i < 8; ++i) {
                sv[i] += __shfl_xor(sv[i], d);
                qv[i] += __shfl_xor(qv[i], d);
            }
        }
        if ((lane & 60) == 0) {  // lanes 0..3 of waves 0,1
#pragma unroll
            for (int i = 0; i < 8; ++i) {
                atomicAdd(&lst[c0 + i], sv[i]);
                atomicAdd(&lst[32 + c0 + i], qv[i]);
            }
        }
    }
    __syncthreads();
    if (tid < 64)
        atomicAdd(&spart[(blockIdx.x & (NCOPY - 1)) * 64 + tid], lst[tid]);
}

// BN+ReLU apply. Prolog: finalize stats from NCOPY partial copies -> LDS.
template <bool WF32, bool WBF>
__global__ __launch_bounds__(256) void k_bn(
    const __bf16* __restrict__ src, const float* __restrict__ spart,
    const float* __restrict__ gamma, const float* __restrict__ beta,
    float inv_cnt, int nrows,
    float* __restrict__ dstf, __bf16* __restrict__ dstb) {
    __shared__ float ss[64];
    __shared__ float sc[32], sh[32];
    const int tid = threadIdx.x;
    if (tid < 64) {
        float a = 0.f;
#pragma unroll
        for (int i = 0; i < NCOPY; ++i) a += spart[i * 64 + tid];
        ss[tid] = a;
    }
    __syncthreads();
    if (tid < 32) {
        float mu = ss[tid] * inv_cnt;
        float var = ss[32 + tid] * inv_cnt - mu * mu;
        float s = gamma[tid] * rsqrtf(var + EPSV);
        sc[tid] = s;
        sh[tid] = beta[tid] - mu * s;
    }
    __syncthreads();
    const int gtid = blockIdx.x * blockDim.x + tid;
    const int c0 = (gtid & 3) * 8;
    float scale[8], shift[8];
#pragma unroll
    for (int i = 0; i < 8; ++i) { scale[i] = sc[c0 + i]; shift[i] = sh[c0 + i]; }
    const int rstride = (gridDim.x * blockDim.x) >> 2;
    for (int r = gtid >> 2; r < nrows; r += rstride) {
        const int off = r * 32 + c0;
        bf16_8 v = *(const bf16_8*)(src + off);
        float y[8];
#pragma unroll
        for (int i = 0; i < 8; ++i) y[i] = fmaxf(fmaf((float)v[i], scale[i], shift[i]), 0.f);
        if (WBF) {
            bf16_8 o;
#pragma unroll
            for (int i = 0; i < 8; ++i) o[i] = (__bf16)y[i];
            *(bf16_8*)(dstb + off) = o;
        }
        if (WF32) {
            f32x4 lo, hi;
#pragma unroll
            for (int i = 0; i < 4; ++i) { lo[i] = y[i]; hi[i] = y[4 + i]; }
            *(f32x4*)(dstf + off) = lo;
            *(f32x4*)(dstf + off + 4) = hi;
        }
    }
}

extern "C" void kernel_launch(void* const* d_in, const int* in_sizes, int n_in,
                              void* d_out, int out_size, void* d_ws, size_t ws_size,
                              hipStream_t stream) {
    const float* feats = (const float*)d_in[0];
    const int* nbr     = (const int*)d_in[1];
    const int* child   = (const int*)d_in[2];
    const float* W1  = (const float*)d_in[3];
    const float* W2a = (const float*)d_in[4];
    const float* W2b = (const float*)d_in[5];
    const float* W3  = (const float*)d_in[6];
    const float* g1 = (const float*)d_in[7];  const float* b1 = (const float*)d_in[8];
    const float* g2 = (const float*)d_in[9];  const float* b2 = (const float*)d_in[10];
    const float* g3 = (const float*)d_in[11]; const float* b3 = (const float*)d_in[12];
    const float* g4 = (const float*)d_in[13]; const float* b4 = (const float*)d_in[14];

    const int N = in_sizes[0] / 3;   // 131072
    const int M = in_sizes[2] / 8;   // output sites of strided conv

    float* outp = (float*)d_out;               // [M,32]
    float* ft2p = outp + (size_t)M * 32;       // [N,32]

    char* ws = (char*)d_ws;
    float* statsAll = (float*)ws;              // 4 stages x NCOPY x 64
    __bf16* w1t  = (__bf16*)(ws + 32768);
    __bf16* w2at = w1t + 27648;
    __bf16* w2bt = w2at + 27648;
    __bf16* w3t  = w2bt + 27648;
    __bf16* X  = (__bf16*)(ws + 32768 + 182272);
    __bf16* T  = X + (size_t)N * 32;
    __bf16* FB = T + (size_t)N * 32;

    float* s1 = statsAll;
    float* s2 = statsAll + NCOPY * 64;
    float* s3 = statsAll + 2 * NCOPY * 64;
    float* s4 = statsAll + 3 * NCOPY * 64;

    k_zero<<<(4 * NCOPY * 64 + 255) / 256, 256, 0, stream>>>(statsAll, 4 * NCOPY * 64);
    k_prepw<<<(91136 + 255) / 256, 256, 0, stream>>>(W1, W2a, W2b, W3, w1t, w2at, w2bt, w3t);
    k_prepf<<<(N * 32 + 255) / 256, 256, 0, stream>>>(feats, FB, N * 32);

    const int cgrid = (N + 31) / 32;    // 32 sites/block, split-K over 4 waves
    const int cgrid3 = (M + 31) / 32;

    // x1 = conv1(featsb)            FB -> X, stats s1
    k_conv<27, false><<<cgrid, 256, 0, stream>>>(FB, nbr, w1t, nullptr, X, s1, N);
    // t1 = bnrelu(x1)               X -> T
    k_bn<false, true><<<1024, 256, 0, stream>>>(X, s1, g1, b1, 1.f / N, N, nullptr, T);
    // br1 = conv2a(t1)              T -> FB, stats s2
    k_conv<27, false><<<cgrid, 256, 0, stream>>>(T, nbr, w2at, nullptr, FB, s2, N);
    // t2 = bnrelu(br1)              FB -> T
    k_bn<false, true><<<1024, 256, 0, stream>>>(FB, s2, g2, b2, 1.f / N, N, nullptr, T);
    // s = x1 + conv2b(t2)           T (+X) -> FB, stats s3
    k_conv<27, true><<<cgrid, 256, 0, stream>>>(T, nbr, w2bt, X, FB, s3, N);
    // ft2 = bnrelu(s)               FB -> d_out(ft2) fp32 + T bf16
    k_bn<true, true><<<1024, 256, 0, stream>>>(FB, s3, g3, b3, 1.f / N, N, ft2p, T);
    // x3 = conv3(ft2)               T -> FB, stats s4
    k_conv<8, false><<<cgrid3, 256, 0, stream>>>(T, child, w3t, nullptr, FB, s4, M);
    // out = bnrelu(x3)              FB -> d_out(out) fp32
    k_bn<true, false><<<1024, 256, 0, stream>>>(FB, s4, g4, b4, 1.f / M, M, outp, nullptr);
}